// Round 1
// baseline (5595.488 us; speedup 1.0000x reference)
//
#include <hip/hip_runtime.h>
#include <cmath>

#define T_LEN 512
#define BS    64
#define F_DIM 128
#define HSZ   256
#define DA    64
#define RH    8
#define KTOT  384   // F + HS

#define NGRP  8     // batch groups
#define NBG   8     // batches per group
#define NHSB  32    // hs-blocks per group
#define HSPB  8     // hs per block
#define NCOL  32    // gate cols per block (4 types x 8 hs)
#define CNT_STRIDE 513

// output offsets (floats)
#define OFF_HT   8388608
#define OFF_CT   8404992
#define OFF_ATT  8421376

// ---------------- K1: scores = tanh(x@W1^T + b1)@W2^T + b2 ----------------
__global__ __launch_bounds__(256) void k_scores(
    const float* __restrict__ x, const float* __restrict__ w1,
    const float* __restrict__ b1, const float* __restrict__ w2,
    const float* __restrict__ b2, float* __restrict__ scores)
{
  __shared__ float wl[DA * 129];   // padded stride 129 -> conflict-free
  __shared__ float xs[4][F_DIM];
  __shared__ float hid[4][DA];
  int tid = threadIdx.x;
  for (int id = tid; id < DA * F_DIM; id += 256) {
    int a = id >> 7, f = id & 127;
    wl[a * 129 + f] = w1[id];
  }
  int wv = tid >> 6, lane = tid & 63;
  int pair = blockIdx.x * 4 + wv;          // pair = b*512 + t
  const float* xr = x + (size_t)pair * F_DIM;
  xs[wv][lane]      = xr[lane];
  xs[wv][64 + lane] = xr[64 + lane];
  __syncthreads();
  float acc = b1[lane];
  #pragma unroll 8
  for (int f = 0; f < F_DIM; ++f)
    acc += xs[wv][f] * wl[lane * 129 + f];
  hid[wv][lane] = tanhf(acc);
  __syncthreads();
  if (lane < RH) {
    float sc = b2[lane];
    #pragma unroll 8
    for (int a = 0; a < DA; ++a)
      sc += hid[wv][a] * w2[lane * DA + a];
    scores[(size_t)pair * RH + lane] = sc;
  }
}

// ------- K2: per-batch softmax prefix sums -> M, plus attention output -------
__global__ __launch_bounds__(512) void k_attn_M(
    const float* __restrict__ x, const float* __restrict__ scores,
    float* __restrict__ M, float* __restrict__ out)
{
  __shared__ float se[T_LEN * 9];    // exp(scores - gmax), padded stride 9
  __shared__ float ivd[T_LEN * 9];   // 1 / cumsum(e)
  __shared__ float cp[4 * F_DIM * RH];
  __shared__ float gmax[RH];
  int tid = threadIdx.x;
  int b = blockIdx.x;
  const float* sb = scores + (size_t)b * T_LEN * RH;
  for (int id = tid; id < T_LEN * RH; id += 512)
    se[(id >> 3) * 9 + (id & 7)] = sb[id];
  __syncthreads();
  {  // per-r global max (valid for all windows since window-max <= global max)
    int w = tid >> 6, l = tid & 63;
    float m = -INFINITY;
    #pragma unroll
    for (int i = 0; i < 8; ++i)
      m = fmaxf(m, se[(i * 64 + l) * 9 + w]);
    #pragma unroll
    for (int off = 32; off; off >>= 1)
      m = fmaxf(m, __shfl_xor(m, off));
    if (l == 0) gmax[w] = m;
  }
  __syncthreads();
  for (int id = tid; id < T_LEN * RH; id += 512) {
    int t = id >> 3, r = id & 7;
    se[t * 9 + r] = expf(se[t * 9 + r] - gmax[r]);
  }
  __syncthreads();
  if (tid < RH) {                   // serial cumsum of denominators (8 chains)
    float run = 0.f;
    for (int t = 0; t < T_LEN; ++t) {
      run += se[t * 9 + tid];
      ivd[t * 9 + tid] = run;
    }
  }
  __syncthreads();
  for (int id = tid; id < T_LEN * RH; id += 512) {
    int t = id >> 3, r = id & 7;
    ivd[t * 9 + r] = 1.f / ivd[t * 9 + r];
  }
  __syncthreads();
  // attention output: full-window softmax, layout [b][r][t]
  for (int id = tid; id < T_LEN * RH; id += 512) {
    int r = id >> 9, t = id & 511;
    out[OFF_ATT + ((size_t)b * RH + r) * T_LEN + t] = se[t * 9 + r] * ivd[511 * 9 + r];
  }
  // M[b,t,f] = (1/8) sum_r cumsum_t(e*x) * ivd  -- chunked prefix over t
  int j = tid >> 7, f = tid & 127;     // 4 t-chunks x 128 f
  const float* xb = x + (size_t)b * T_LEN * F_DIM;
  float part[RH];
  #pragma unroll
  for (int r = 0; r < RH; ++r) part[r] = 0.f;
  for (int t = j * 128; t < j * 128 + 128; ++t) {
    float xv = xb[t * F_DIM + f];
    #pragma unroll
    for (int r = 0; r < RH; ++r) part[r] += se[t * 9 + r] * xv;
  }
  {
    float* c = &cp[(j * F_DIM + f) * RH];
    #pragma unroll
    for (int r = 0; r < RH; ++r) c[r] = part[r];
  }
  __syncthreads();
  float num[RH];
  #pragma unroll
  for (int r = 0; r < RH; ++r) num[r] = 0.f;
  for (int jj = 0; jj < j; ++jj) {
    const float* c = &cp[(jj * F_DIM + f) * RH];
    #pragma unroll
    for (int r = 0; r < RH; ++r) num[r] += c[r];
  }
  float* Mb = M + (size_t)b * T_LEN * F_DIM;
  for (int t = j * 128; t < j * 128 + 128; ++t) {
    float xv = xb[t * F_DIM + f];
    float acc = 0.f;
    #pragma unroll
    for (int r = 0; r < RH; ++r) {
      num[r] += se[t * 9 + r] * xv;
      acc += num[r] * ivd[t * 9 + r];
    }
    Mb[t * F_DIM + f] = 0.125f * acc;
  }
}

// ---------------- K4: recurrent loop, persistent cooperative ----------------
__device__ __forceinline__ void grp_barrier(unsigned int* cnt, int slot)
{
  __syncthreads();
  if (threadIdx.x == 0) {
    __hip_atomic_fetch_add(cnt + slot, 1u, __ATOMIC_RELEASE, __HIP_MEMORY_SCOPE_AGENT);
    while (__hip_atomic_load(cnt + slot, __ATOMIC_ACQUIRE, __HIP_MEMORY_SCOPE_AGENT) < NHSB)
      __builtin_amdgcn_s_sleep(2);
  }
  __syncthreads();
}

__global__ __launch_bounds__(256) void k_lstm(
    const float* __restrict__ M, const float* __restrict__ Wi,
    const float* __restrict__ Wh, const float* __restrict__ bias,
    float* __restrict__ h_buf, unsigned int* __restrict__ cnt,
    float* __restrict__ out)
{
  __shared__ float Wl[KTOT * NCOL];   // 48KB persistent W_cat slice
  __shared__ float v[KTOT * 9];       // [M_t ; h_prev], stride-9 padded
  __shared__ float part[8 * 256];
  __shared__ float gates[256];
  __shared__ float bias_s[NCOL];
  int tid = threadIdx.x;
  int blk = blockIdx.x;
  int g = blk >> 5, s = blk & 31;     // batch group / hs-slice
  int hs0 = s * HSPB;
  int b0 = g * NBG;
  unsigned int* gcnt = cnt + g * CNT_STRIDE;

  for (int id = tid; id < KTOT * NCOL; id += 256) {
    int k = id >> 5, c = id & 31;
    int gcol = ((c >> 3) << 8) + hs0 + (c & 7);
    Wl[id] = (k < F_DIM) ? Wi[k * 1024 + gcol] : Wh[(k - F_DIM) * 1024 + gcol];
  }
  if (tid < NCOL) bias_s[tid] = bias[((tid >> 3) << 8) + hs0 + (tid & 7)];
  if (tid < NBG * HSPB) {             // zero h buffer parity-1 (read at t=0)
    int b = tid >> 3, jj = tid & 7;
    h_buf[(BS + b0 + b) * HSZ + hs0 + jj] = 0.f;
  }
  grp_barrier(gcnt, T_LEN);           // init barrier (slot 512)

  int kc = tid >> 5, sub = tid & 31;  // 8 k-chunks x (4 batch-pairs x 8 col-quads)
  int b2 = sub >> 3, c4 = sub & 7;
  int bA = 2 * b2, bB = bA + 1;
  int kbase = kc * 48;
  int ub = tid >> 3, uj = tid & 7;    // update cell (tid<64)
  float c_reg = 0.f;

  for (int t = 0; t < T_LEN; ++t) {
    {  // stage v = [M_t ; h_{t-1}] for this block's 8 batches
      int f = tid & 127, bb = tid >> 7;
      #pragma unroll
      for (int i = 0; i < 4; ++i) {
        int b = bb + 2 * i;
        v[f * 9 + b] = M[((size_t)(b0 + b) * T_LEN + t) * F_DIM + f];
      }
      int b = tid >> 5, k0 = (tid & 31) * 8;
      const float* hp = &h_buf[(((t + 1) & 1) * BS + b0 + b) * HSZ + k0];
      #pragma unroll
      for (int i = 0; i < 8; ++i)
        v[(F_DIM + k0 + i) * 9 + b] = hp[i];
    }
    __syncthreads();
    float4 a0 = {0, 0, 0, 0}, a1 = {0, 0, 0, 0};
    for (int kk = 0; kk < 48; ++kk) {
      int k = kbase + kk;
      float4 w4 = *(const float4*)&Wl[k * NCOL + c4 * 4];
      float hA = v[k * 9 + bA];
      float hB = v[k * 9 + bB];
      a0.x += hA * w4.x; a0.y += hA * w4.y; a0.z += hA * w4.z; a0.w += hA * w4.w;
      a1.x += hB * w4.x; a1.y += hB * w4.y; a1.z += hB * w4.z; a1.w += hB * w4.w;
    }
    *(float4*)&part[kc * 256 + bA * 32 + c4 * 4] = a0;
    *(float4*)&part[kc * 256 + bB * 32 + c4 * 4] = a1;
    __syncthreads();
    {
      float sum = 0.f;
      #pragma unroll
      for (int q = 0; q < 8; ++q) sum += part[q * 256 + tid];
      gates[tid] = sum + bias_s[tid & 31];
    }
    __syncthreads();
    if (tid < 64) {
      float gi = gates[ub * 32 + uj];
      float gf = gates[ub * 32 + 8 + uj];
      float gg = gates[ub * 32 + 16 + uj];
      float go = gates[ub * 32 + 24 + uj];
      float ii = 1.f / (1.f + expf(-gi));
      float ff = 1.f / (1.f + expf(-gf));
      float gt = tanhf(gg);
      float oo = 1.f / (1.f + expf(-go));
      c_reg = ff * c_reg + ii * gt;
      float h = oo * tanhf(c_reg);
      int b = b0 + ub, hsx = hs0 + uj;
      h_buf[((t & 1) * BS + b) * HSZ + hsx] = h;
      out[((size_t)b * T_LEN + t) * HSZ + hsx] = h;
      if (t == T_LEN - 1) {
        out[OFF_HT + b * HSZ + hsx] = h;
        out[OFF_CT + b * HSZ + hsx] = c_reg;
      }
    }
    grp_barrier(gcnt, t);
  }
}

extern "C" void kernel_launch(void* const* d_in, const int* in_sizes, int n_in,
                              void* d_out, int out_size, void* d_ws, size_t ws_size,
                              hipStream_t stream) {
  const float* x   = (const float*)d_in[0];
  const float* w1  = (const float*)d_in[1];
  const float* b1  = (const float*)d_in[2];
  const float* w2  = (const float*)d_in[3];
  const float* b2  = (const float*)d_in[4];
  const float* Wi  = (const float*)d_in[5];
  const float* Wh  = (const float*)d_in[6];
  const float* bia = (const float*)d_in[7];
  float* out = (float*)d_out;
  float* ws  = (float*)d_ws;

  float* scores = ws;                                    // 262144
  float* M      = ws + 262144;                           // 4194304
  float* h_buf  = ws + 262144 + 4194304;                 // 32768
  unsigned int* cnt = (unsigned int*)(ws + 262144 + 4194304 + 32768);  // 8*513

  hipMemsetAsync(cnt, 0, NGRP * CNT_STRIDE * sizeof(unsigned int), stream);
  hipLaunchKernelGGL(k_scores, dim3(8192), dim3(256), 0, stream,
                     x, w1, b1, w2, b2, scores);
  hipLaunchKernelGGL(k_attn_M, dim3(64), dim3(512), 0, stream,
                     x, scores, M, out);

  const float* Mp = M; const float* Wip = Wi; const float* Whp = Wh;
  const float* biap = bia; float* hbp = h_buf; unsigned int* cntp = cnt;
  float* outp = out;
  void* args[] = {&Mp, &Wip, &Whp, &biap, &hbp, &cntp, &outp};
  hipError_t err = hipLaunchCooperativeKernel((const void*)k_lstm,
                     dim3(NGRP * NHSB), dim3(256), args, 0, stream);
  if (err != hipSuccess) {
    // fallback: plain launch (256 blocks of 256 thr co-reside on 256 CUs)
    hipLaunchKernelGGL(k_lstm, dim3(NGRP * NHSB), dim3(256), 0, stream,
                       Mp, Wip, Whp, biap, hbp, cntp, outp);
  }
}

// Round 2
// 4593.205 us; speedup vs baseline: 1.2182x; 1.2182x over previous
//
#include <hip/hip_runtime.h>
#include <cmath>

#define T_LEN 512
#define BS    64
#define F_DIM 128
#define HSZ   256
#define DA    64
#define RH    8
#define KTOT  384   // F + HS

// output offsets (floats)
#define OFF_HT   8388608
#define OFF_CT   8404992
#define OFF_ATT  8421376

// ---------------- K1: scores = tanh(x@W1^T + b1)@W2^T + b2 ----------------
__global__ __launch_bounds__(256) void k_scores(
    const float* __restrict__ x, const float* __restrict__ w1,
    const float* __restrict__ b1, const float* __restrict__ w2,
    const float* __restrict__ b2, float* __restrict__ scores)
{
  __shared__ float wl[DA * 129];   // padded stride 129 -> conflict-free
  __shared__ float xs[4][F_DIM];
  __shared__ float hid[4][DA];
  int tid = threadIdx.x;
  for (int id = tid; id < DA * F_DIM; id += 256) {
    int a = id >> 7, f = id & 127;
    wl[a * 129 + f] = w1[id];
  }
  int wv = tid >> 6, lane = tid & 63;
  int pair = blockIdx.x * 4 + wv;          // pair = b*512 + t
  const float* xr = x + (size_t)pair * F_DIM;
  xs[wv][lane]      = xr[lane];
  xs[wv][64 + lane] = xr[64 + lane];
  __syncthreads();
  float acc = b1[lane];
  #pragma unroll 8
  for (int f = 0; f < F_DIM; ++f)
    acc += xs[wv][f] * wl[lane * 129 + f];
  hid[wv][lane] = tanhf(acc);
  __syncthreads();
  if (lane < RH) {
    float sc = b2[lane];
    #pragma unroll 8
    for (int a = 0; a < DA; ++a)
      sc += hid[wv][a] * w2[lane * DA + a];
    scores[(size_t)pair * RH + lane] = sc;
  }
}

// ------- K2: per-batch softmax prefix sums -> M, plus attention output -------
__global__ __launch_bounds__(512) void k_attn_M(
    const float* __restrict__ x, const float* __restrict__ scores,
    float* __restrict__ M, float* __restrict__ out)
{
  __shared__ float se[T_LEN * 9];    // exp(scores - gmax), padded stride 9
  __shared__ float ivd[T_LEN * 9];   // 1 / cumsum(e)
  __shared__ float cp[4 * F_DIM * RH];
  __shared__ float gmax[RH];
  int tid = threadIdx.x;
  int b = blockIdx.x;
  const float* sb = scores + (size_t)b * T_LEN * RH;
  for (int id = tid; id < T_LEN * RH; id += 512)
    se[(id >> 3) * 9 + (id & 7)] = sb[id];
  __syncthreads();
  {  // per-r global max (valid for all windows since window-max <= global max)
    int w = tid >> 6, l = tid & 63;
    float m = -INFINITY;
    #pragma unroll
    for (int i = 0; i < 8; ++i)
      m = fmaxf(m, se[(i * 64 + l) * 9 + w]);
    #pragma unroll
    for (int off = 32; off; off >>= 1)
      m = fmaxf(m, __shfl_xor(m, off));
    if (l == 0) gmax[w] = m;
  }
  __syncthreads();
  for (int id = tid; id < T_LEN * RH; id += 512) {
    int t = id >> 3, r = id & 7;
    se[t * 9 + r] = expf(se[t * 9 + r] - gmax[r]);
  }
  __syncthreads();
  if (tid < RH) {                   // serial cumsum of denominators (8 chains)
    float run = 0.f;
    for (int t = 0; t < T_LEN; ++t) {
      run += se[t * 9 + tid];
      ivd[t * 9 + tid] = run;
    }
  }
  __syncthreads();
  for (int id = tid; id < T_LEN * RH; id += 512) {
    int t = id >> 3, r = id & 7;
    ivd[t * 9 + r] = 1.f / ivd[t * 9 + r];
  }
  __syncthreads();
  // attention output: full-window softmax, layout [b][r][t]
  for (int id = tid; id < T_LEN * RH; id += 512) {
    int r = id >> 9, t = id & 511;
    out[OFF_ATT + ((size_t)b * RH + r) * T_LEN + t] = se[t * 9 + r] * ivd[511 * 9 + r];
  }
  // M[b,t,f] = (1/8) sum_r cumsum_t(e*x) * ivd  -- chunked prefix over t
  int j = tid >> 7, f = tid & 127;     // 4 t-chunks x 128 f
  const float* xb = x + (size_t)b * T_LEN * F_DIM;
  float part[RH];
  #pragma unroll
  for (int r = 0; r < RH; ++r) part[r] = 0.f;
  for (int t = j * 128; t < j * 128 + 128; ++t) {
    float xv = xb[t * F_DIM + f];
    #pragma unroll
    for (int r = 0; r < RH; ++r) part[r] += se[t * 9 + r] * xv;
  }
  {
    float* c = &cp[(j * F_DIM + f) * RH];
    #pragma unroll
    for (int r = 0; r < RH; ++r) c[r] = part[r];
  }
  __syncthreads();
  float num[RH];
  #pragma unroll
  for (int r = 0; r < RH; ++r) num[r] = 0.f;
  for (int jj = 0; jj < j; ++jj) {
    const float* c = &cp[(jj * F_DIM + f) * RH];
    #pragma unroll
    for (int r = 0; r < RH; ++r) num[r] += c[r];
  }
  float* Mb = M + (size_t)b * T_LEN * F_DIM;
  for (int t = j * 128; t < j * 128 + 128; ++t) {
    float xv = xb[t * F_DIM + f];
    float acc = 0.f;
    #pragma unroll
    for (int r = 0; r < RH; ++r) {
      num[r] += se[t * 9 + r] * xv;
      acc += num[r] * ivd[t * 9 + r];
    }
    Mb[t * F_DIM + f] = 0.125f * acc;
  }
}

// ---------------- K3: recurrent loop, 4 blocks/batch, flag sync ----------------
// blk = s*64 + b  (s = col-slice 0..3, b = batch 0..63) -> same-XCD pairing
// thread: half = tid>>8 (K-split 0..191 / 192..383), ct = tid&255,
//         col = (ct>>6)*256 + s*64 + (ct&63); 192 fp32 weights in registers.
__global__ __launch_bounds__(512, 2) void k_lstm(
    const float* __restrict__ M, const float* __restrict__ Wi,
    const float* __restrict__ Wh, const float* __restrict__ bias,
    float* __restrict__ slab, unsigned int* __restrict__ flags,
    float* __restrict__ out)
{
  __shared__ float v[HSZ];       // h_{t-1}, all 256
  __shared__ float mst[F_DIM];   // M[b,t,:]
  __shared__ float part[512];    // per-thread partials
  int tid = threadIdx.x;
  int blk = blockIdx.x;
  int s = blk >> 6;              // col slice
  int b = blk & 63;              // batch
  int half = tid >> 8;
  int ct = tid & 255;
  int type = ct >> 6, j = ct & 63;
  int col = type * 256 + s * 64 + j;

  // --- weights into registers (static-indexed, stays in VGPRs) ---
  float w[192];
  {
    int k0 = half * 192;
    #pragma unroll
    for (int k = 0; k < 192; ++k) {
      int kk = k0 + k;
      w[k] = (kk < F_DIM) ? Wi[(size_t)kk * 1024 + col]
                          : Wh[(size_t)(kk - F_DIM) * 1024 + col];
    }
  }
  float bsum = bias[col];
  float c_reg = 0.f;

  if (tid < HSZ) v[tid] = 0.f;
  if (tid < F_DIM) mst[tid] = M[((size_t)b * T_LEN) * F_DIM + tid];
  __syncthreads();

  unsigned int* bf = flags + b * 4;

  for (int t = 0; t < T_LEN; ++t) {
    // --- phase 1: gate partials (K split across halves) ---
    float acc;
    if (half == 0) {
      acc = bsum;
      #pragma unroll
      for (int k = 0; k < 128; ++k) acc += mst[k] * w[k];
      #pragma unroll
      for (int k = 128; k < 192; ++k) acc += v[k - 128] * w[k];
    } else {
      acc = 0.f;
      #pragma unroll
      for (int k = 0; k < 192; ++k) acc += v[64 + k] * w[k];
    }
    part[tid] = acc;
    __syncthreads();

    // --- phase 2: update cells (wave 0), publish h slice + flag ---
    if (tid < 64) {
      float gi = part[tid]       + part[256 + tid];
      float gf = part[64 + tid]  + part[320 + tid];
      float gg = part[128 + tid] + part[384 + tid];
      float go = part[192 + tid] + part[448 + tid];
      float ii = 1.f / (1.f + expf(-gi));
      float ff = 1.f / (1.f + expf(-gf));
      float gt = tanhf(gg);
      float oo = 1.f / (1.f + expf(-go));
      c_reg = ff * c_reg + ii * gt;
      float h = oo * tanhf(c_reg);
      int hsx = s * 64 + tid;
      v[hsx] = h;   // own slice for next step (ordered vs phase-1 reads by sync above)
      slab[(((t & 1) * BS + b) * HSZ) + hsx] = h;
      out[((size_t)b * T_LEN + t) * HSZ + hsx] = h;
      if (t == T_LEN - 1) {
        out[OFF_HT + b * HSZ + hsx] = h;
        out[OFF_CT + b * HSZ + hsx] = c_reg;
      }
    }
    if (tid == 0) {   // release: wave0's slab stores drained before flag
      __threadfence();
      __hip_atomic_store(bf + s, (unsigned)(t + 1), __ATOMIC_RELAXED,
                         __HIP_MEMORY_SCOPE_AGENT);
    }

    if (t < T_LEN - 1) {
      // --- phase 3: prefetch M[t+1] (latency overlaps partner wait) ---
      float mreg = 0.f;
      if (tid < F_DIM)
        mreg = M[((size_t)b * T_LEN + t + 1) * F_DIM + tid];
      // --- phase 4: wait partners (3 lanes poll in parallel), acquire ---
      if (tid < 4 && tid != s) {
        while (__hip_atomic_load(bf + tid, __ATOMIC_RELAXED,
                                 __HIP_MEMORY_SCOPE_AGENT) <= (unsigned)t)
          __builtin_amdgcn_s_sleep(1);
      }
      if (tid == 0) __threadfence();   // acquire: invalidate L1 before slab reads
      __syncthreads();
      // --- phase 5: read partner h slices, stage M ---
      if (tid < 192) {
        int idx = tid >> 6;
        int sp = idx + (idx >= s);     // the 3 partner slices
        int hsx = sp * 64 + (tid & 63);
        v[hsx] = slab[(((t & 1) * BS + b) * HSZ) + hsx];
      }
      if (tid < F_DIM) mst[tid] = mreg;
      __syncthreads();
    }
  }
}

extern "C" void kernel_launch(void* const* d_in, const int* in_sizes, int n_in,
                              void* d_out, int out_size, void* d_ws, size_t ws_size,
                              hipStream_t stream) {
  const float* x   = (const float*)d_in[0];
  const float* w1  = (const float*)d_in[1];
  const float* b1  = (const float*)d_in[2];
  const float* w2  = (const float*)d_in[3];
  const float* b2  = (const float*)d_in[4];
  const float* Wi  = (const float*)d_in[5];
  const float* Wh  = (const float*)d_in[6];
  const float* bia = (const float*)d_in[7];
  float* out = (float*)d_out;
  float* ws  = (float*)d_ws;

  float* scores = ws;                                    // 262144 f
  float* M      = ws + 262144;                           // 4194304 f
  float* slab   = ws + 262144 + 4194304;                 // 2*64*256 f
  unsigned int* flags = (unsigned int*)(ws + 262144 + 4194304 + 32768);  // 256 u32

  hipMemsetAsync(flags, 0, 256 * sizeof(unsigned int), stream);
  hipLaunchKernelGGL(k_scores, dim3(8192), dim3(256), 0, stream,
                     x, w1, b1, w2, b2, scores);
  hipLaunchKernelGGL(k_attn_M, dim3(64), dim3(512), 0, stream,
                     x, scores, M, out);
  hipLaunchKernelGGL(k_lstm, dim3(256), dim3(512), 0, stream,
                     M, Wi, Wh, bia, slab, flags, out);
}

// Round 3
// 1196.339 us; speedup vs baseline: 4.6772x; 3.8394x over previous
//
#include <hip/hip_runtime.h>
#include <cmath>

#define T_LEN 512
#define BS    64
#define F_DIM 128
#define HSZ   256
#define DA    64
#define RH    8
#define KTOT  384   // F + HS

// output offsets (floats)
#define OFF_HT   8388608
#define OFF_CT   8404992
#define OFF_ATT  8421376

// ---------------- K1: scores = tanh(x@W1^T + b1)@W2^T + b2 ----------------
__global__ __launch_bounds__(256) void k_scores(
    const float* __restrict__ x, const float* __restrict__ w1,
    const float* __restrict__ b1, const float* __restrict__ w2,
    const float* __restrict__ b2, float* __restrict__ scores)
{
  __shared__ float wl[DA * 129];   // padded stride 129 -> conflict-free
  __shared__ float xs[4][F_DIM];
  __shared__ float hid[4][DA];
  int tid = threadIdx.x;
  for (int id = tid; id < DA * F_DIM; id += 256) {
    int a = id >> 7, f = id & 127;
    wl[a * 129 + f] = w1[id];
  }
  int wv = tid >> 6, lane = tid & 63;
  int pair = blockIdx.x * 4 + wv;          // pair = b*512 + t
  const float* xr = x + (size_t)pair * F_DIM;
  xs[wv][lane]      = xr[lane];
  xs[wv][64 + lane] = xr[64 + lane];
  __syncthreads();
  float acc = b1[lane];
  #pragma unroll 8
  for (int f = 0; f < F_DIM; ++f)
    acc += xs[wv][f] * wl[lane * 129 + f];
  hid[wv][lane] = tanhf(acc);
  __syncthreads();
  if (lane < RH) {
    float sc = b2[lane];
    #pragma unroll 8
    for (int a = 0; a < DA; ++a)
      sc += hid[wv][a] * w2[lane * DA + a];
    scores[(size_t)pair * RH + lane] = sc;
  }
}

// ------- K2: per-batch softmax prefix sums -> M, plus attention output -------
__global__ __launch_bounds__(512) void k_attn_M(
    const float* __restrict__ x, const float* __restrict__ scores,
    float* __restrict__ M, float* __restrict__ out)
{
  __shared__ float se[T_LEN * 9];    // exp(scores - gmax), padded stride 9
  __shared__ float ivd[T_LEN * 9];   // 1 / cumsum(e)
  __shared__ float cp[4 * F_DIM * RH];
  __shared__ float gmax[RH];
  int tid = threadIdx.x;
  int b = blockIdx.x;
  const float* sb = scores + (size_t)b * T_LEN * RH;
  for (int id = tid; id < T_LEN * RH; id += 512)
    se[(id >> 3) * 9 + (id & 7)] = sb[id];
  __syncthreads();
  {  // per-r global max (valid for all windows since window-max <= global max)
    int w = tid >> 6, l = tid & 63;
    float m = -INFINITY;
    #pragma unroll
    for (int i = 0; i < 8; ++i)
      m = fmaxf(m, se[(i * 64 + l) * 9 + w]);
    #pragma unroll
    for (int off = 32; off; off >>= 1)
      m = fmaxf(m, __shfl_xor(m, off));
    if (l == 0) gmax[w] = m;
  }
  __syncthreads();
  for (int id = tid; id < T_LEN * RH; id += 512) {
    int t = id >> 3, r = id & 7;
    se[t * 9 + r] = expf(se[t * 9 + r] - gmax[r]);
  }
  __syncthreads();
  if (tid < RH) {                   // serial cumsum of denominators (8 chains)
    float run = 0.f;
    for (int t = 0; t < T_LEN; ++t) {
      run += se[t * 9 + tid];
      ivd[t * 9 + tid] = run;
    }
  }
  __syncthreads();
  for (int id = tid; id < T_LEN * RH; id += 512) {
    int t = id >> 3, r = id & 7;
    ivd[t * 9 + r] = 1.f / ivd[t * 9 + r];
  }
  __syncthreads();
  // attention output: full-window softmax, layout [b][r][t]
  for (int id = tid; id < T_LEN * RH; id += 512) {
    int r = id >> 9, t = id & 511;
    out[OFF_ATT + ((size_t)b * RH + r) * T_LEN + t] = se[t * 9 + r] * ivd[511 * 9 + r];
  }
  // M[b,t,f] = (1/8) sum_r cumsum_t(e*x) * ivd  -- chunked prefix over t
  int j = tid >> 7, f = tid & 127;     // 4 t-chunks x 128 f
  const float* xb = x + (size_t)b * T_LEN * F_DIM;
  float part[RH];
  #pragma unroll
  for (int r = 0; r < RH; ++r) part[r] = 0.f;
  for (int t = j * 128; t < j * 128 + 128; ++t) {
    float xv = xb[t * F_DIM + f];
    #pragma unroll
    for (int r = 0; r < RH; ++r) part[r] += se[t * 9 + r] * xv;
  }
  {
    float* c = &cp[(j * F_DIM + f) * RH];
    #pragma unroll
    for (int r = 0; r < RH; ++r) c[r] = part[r];
  }
  __syncthreads();
  float num[RH];
  #pragma unroll
  for (int r = 0; r < RH; ++r) num[r] = 0.f;
  for (int jj = 0; jj < j; ++jj) {
    const float* c = &cp[(jj * F_DIM + f) * RH];
    #pragma unroll
    for (int r = 0; r < RH; ++r) num[r] += c[r];
  }
  float* Mb = M + (size_t)b * T_LEN * F_DIM;
  for (int t = j * 128; t < j * 128 + 128; ++t) {
    float xv = xb[t * F_DIM + f];
    float acc = 0.f;
    #pragma unroll
    for (int r = 0; r < RH; ++r) {
      num[r] += se[t * 9 + r] * xv;
      acc += num[r] * ivd[t * 9 + r];
    }
    Mb[t * F_DIM + f] = 0.125f * acc;
  }
}

// ---------------- K3: recurrent loop, fence-free tagged-atomic sync ----------------
// blk = s*64 + b. h values travel INSIDE relaxed agent-scope 64-bit atomics:
// word = (tag=t+1)<<32 | float_bits. Parity double-buffer on t&1; equality poll
// (max skew between partner blocks is 1 step, and 0xAA poison never matches).
__global__ __launch_bounds__(512, 2) void k_lstm(
    const float* __restrict__ M, const float* __restrict__ Wi,
    const float* __restrict__ Wh, const float* __restrict__ bias,
    unsigned long long* __restrict__ slab64,
    float* __restrict__ out)
{
  __shared__ float v[HSZ];       // h_{t-1}, all 256
  __shared__ float mst[F_DIM];   // M[b,t,:]
  __shared__ float part[512];    // per-thread partials
  int tid = threadIdx.x;
  int blk = blockIdx.x;
  int s = blk >> 6;              // col slice
  int b = blk & 63;              // batch
  int half = tid >> 8;
  int ct = tid & 255;
  int type = ct >> 6, j = ct & 63;
  int col = type * 256 + s * 64 + j;

  // --- weights into registers (static-indexed) ---
  float w[192];
  {
    int k0 = half * 192;
    #pragma unroll
    for (int k = 0; k < 192; ++k) {
      int kk = k0 + k;
      w[k] = (kk < F_DIM) ? Wi[(size_t)kk * 1024 + col]
                          : Wh[(size_t)(kk - F_DIM) * 1024 + col];
    }
  }
  float bsum = bias[col];
  float c_reg = 0.f;

  if (tid < HSZ) v[tid] = 0.f;
  if (tid < F_DIM) mst[tid] = M[((size_t)b * T_LEN) * F_DIM + tid];
  __syncthreads();

  // partner-poll assignment: threads 0..191 each own one partner h word
  int pidx = tid >> 6;
  int sp = pidx + (pidx >= s);   // the 3 partner slices
  int pj = tid & 63;

  for (int t = 0; t < T_LEN; ++t) {
    // --- phase 1: gate partials (K split across halves) ---
    float acc;
    if (half == 0) {
      acc = bsum;
      #pragma unroll
      for (int k = 0; k < 128; ++k) acc += mst[k] * w[k];
      #pragma unroll
      for (int k = 128; k < 192; ++k) acc += v[k - 128] * w[k];
    } else {
      acc = 0.f;
      #pragma unroll
      for (int k = 0; k < 192; ++k) acc += v[64 + k] * w[k];
    }
    part[tid] = acc;
    __syncthreads();

    // --- phase 2: cell update (wave 0), publish tagged h words ---
    if (tid < 64) {
      float gi = part[tid]       + part[256 + tid];
      float gf = part[64 + tid]  + part[320 + tid];
      float gg = part[128 + tid] + part[384 + tid];
      float go = part[192 + tid] + part[448 + tid];
      float ii = 1.f / (1.f + expf(-gi));
      float ff = 1.f / (1.f + expf(-gf));
      float gt = tanhf(gg);
      float oo = 1.f / (1.f + expf(-go));
      c_reg = ff * c_reg + ii * gt;
      float h = oo * tanhf(c_reg);
      int hsx = s * 64 + tid;
      v[hsx] = h;   // own slice for next step
      unsigned long long pk =
          ((unsigned long long)(unsigned)(t + 1) << 32) |
          (unsigned long long)__float_as_uint(h);
      __hip_atomic_store(&slab64[(((t & 1) * BS + b) * 4 + s) * 64 + tid], pk,
                         __ATOMIC_RELAXED, __HIP_MEMORY_SCOPE_AGENT);
      out[((size_t)b * T_LEN + t) * HSZ + hsx] = h;
      if (t == T_LEN - 1) {
        out[OFF_HT + b * HSZ + hsx] = h;
        out[OFF_CT + b * HSZ + hsx] = c_reg;
      }
    }

    if (t < T_LEN - 1) {
      // --- phase 3: prefetch M[t+1] (latency overlaps partner wait) ---
      float mreg = 0.f;
      if (tid < F_DIM)
        mreg = M[((size_t)b * T_LEN + t + 1) * F_DIM + tid];
      // --- phase 4: poll partner tagged words (data rides in the atomic) ---
      if (tid < 192) {
        const unsigned long long* addr =
            &slab64[(((t & 1) * BS + b) * 4 + sp) * 64 + pj];
        unsigned want = (unsigned)(t + 1);
        unsigned long long got;
        do {
          got = __hip_atomic_load(addr, __ATOMIC_RELAXED,
                                  __HIP_MEMORY_SCOPE_AGENT);
        } while ((unsigned)(got >> 32) != want);
        v[sp * 64 + pj] = __uint_as_float((unsigned)(got & 0xffffffffu));
      }
      if (tid < F_DIM) mst[tid] = mreg;
      __syncthreads();
    }
  }
}

extern "C" void kernel_launch(void* const* d_in, const int* in_sizes, int n_in,
                              void* d_out, int out_size, void* d_ws, size_t ws_size,
                              hipStream_t stream) {
  const float* x   = (const float*)d_in[0];
  const float* w1  = (const float*)d_in[1];
  const float* b1  = (const float*)d_in[2];
  const float* w2  = (const float*)d_in[3];
  const float* b2  = (const float*)d_in[4];
  const float* Wi  = (const float*)d_in[5];
  const float* Wh  = (const float*)d_in[6];
  const float* bia = (const float*)d_in[7];
  float* out = (float*)d_out;
  float* ws  = (float*)d_ws;

  float* scores = ws;                                    // 262144 f
  float* M      = ws + 262144;                           // 4194304 f
  unsigned long long* slab64 =
      (unsigned long long*)(ws + 262144 + 4194304);      // 2*64*4*64 u64

  hipLaunchKernelGGL(k_scores, dim3(8192), dim3(256), 0, stream,
                     x, w1, b1, w2, b2, scores);
  hipLaunchKernelGGL(k_attn_M, dim3(64), dim3(512), 0, stream,
                     x, scores, M, out);
  hipLaunchKernelGGL(k_lstm, dim3(256), dim3(512), 0, stream,
                     M, Wi, Wh, bia, slab64, out);
}